// Round 16
// baseline (2434.526 us; speedup 1.0000x reference)
//
#include <hip/hip_runtime.h>

#define HIDN 20
#define CHUNK 128
#define WARM 64
#define NB ((CHUNK + WARM) / 64)   // 3 batches of 64 steps
#define WARMB (WARM / 64)          // first batch is warmup

typedef float v2f __attribute__((ext_vector_type(2)));
typedef unsigned int v2u __attribute__((ext_vector_type(2)));

__device__ __forceinline__ float bcast(float v, int l) {
    return __int_as_float(__builtin_amdgcn_readlane(__float_as_int(v), l));
}
__device__ __forceinline__ v2f fma2(v2f a, v2f b, v2f c) {
    return __builtin_elementwise_fma(a, b, c);      // -> v_pk_fma_f32 (all-VGPR)
}
// lane[i] <-> lane[i^32] exchange. Builtin permlane32_swap returns BOTH
// results; with equal inputs the per-lane pair {r.x,r.y} = {g, g[lane^32]}
// under either swap direction, so r.x^r.y^g is the exchanged value --
// bit-exact, direction-agnostic, VALU-pipe (no DS round trip).
__device__ __forceinline__ float xchg32(float g) {
#if __has_builtin(__builtin_amdgcn_permlane32_swap)
    const unsigned int gu = __float_as_uint(g);
    const v2u r = __builtin_amdgcn_permlane32_swap(gu, gu, false, false);
    return __uint_as_float(r.x ^ r.y ^ gu);
#else
    return __shfl_xor(g, 32);
#endif
}

// gate-split LSTM cell epilogue (f32). Half A lanes hold gate pre-acts (i,f),
// half B lanes hold (g,o) for the same unit.
__device__ __forceinline__ float gate_update(float aA, float aB, float& c,
                                             float cA, float mA, float dA,
                                             bool hB) {
    const float cB = -1.4426950408889634f;
    const float cT =  2.8853900817779268f;
    float eA = __builtin_amdgcn_exp2f(cA * aA);
    float sA = __builtin_amdgcn_rcpf(1.0f + eA);
    float gA = __builtin_fmaf(mA, sA, -dA);          // i (half A) / g (half B)
    float eB = __builtin_amdgcn_exp2f(cB * aB);
    float gB = __builtin_amdgcn_rcpf(1.0f + eB);     // f (half A) / o (half B)
    float oA = xchg32(gA);
    float oB = xchg32(gB);
    float f = hB ? oB : gB;
    float o = hB ? gB : oB;
    c = __builtin_fmaf(f, c, gA * oA);
    float ec = __builtin_amdgcn_exp2f(cT * c);
    float tc = 1.0f - 2.0f * __builtin_amdgcn_rcpf(ec + 1.0f);
    return o * tc;
}

#define RJA(M) M(0) M(1) M(2) M(3) M(4)
#define RJB(M) M(5) M(6) M(7) M(8) M(9)
#define RJ(M) RJA(M) RJB(M)

// One 64-lane wave = one chunk of CHUNK=128 steps (+64 warmup). 4096 chunks
// -> 4 waves/SIMD (VGPR<=128), trading 1.2x warmup work for hiding the
// DS-latency stalls that capped 2-wave VALUBusy at 78%.
// Software-pipelined layers (L1(t) ∥ L0(t+1)); h broadcast via 160 B LDS
// buffer; deferred output head via hstore.
__global__ __launch_bounds__(64)
__attribute__((amdgpu_waves_per_eu(4, 4)))
void lstm_opt_kernel(const float* __restrict__ grad, const float* __restrict__ par,
                     const float* __restrict__ Wih0, const float* __restrict__ Whh0,
                     const float* __restrict__ bih0, const float* __restrict__ bhh0,
                     const float* __restrict__ Wih1, const float* __restrict__ Whh1,
                     const float* __restrict__ bih1, const float* __restrict__ bhh1,
                     const float* __restrict__ Wout, const float* __restrict__ bout,
                     float* __restrict__ out, int n)
{
    __shared__ __align__(16) float hbuf[40];        // [0..19]=h0(t), [20..39]=h1(t-1)
    __shared__ __align__(16) float hstore[64][24];  // per-step h1*wo, stride 24

    const int lane  = threadIdx.x;
    const int lh    = lane & 31;
    const bool hB   = lane >= 32;
    const int u     = (lh < HIDN) ? lh : (HIDN - 1);
    const bool valid = (lh < HIDN);
    // invalid lanes park their (zero) head writes in pad columns 20..23
    const int wcol  = valid ? lh : (HIDN + (lane & 3));

    const int rowA = (hB ? 2 : 0) * HIDN + u;   // i-row or g-row
    const int rowB = (hB ? 3 : 1) * HIDN + u;   // f-row or o-row

    // ---- k-paired register weights (named v2f scalars; no arrays) ----
#define DECLW(j) v2f w0A_##j, w0B_##j, wiA_##j, wiB_##j, whA_##j, whB_##j;
    RJ(DECLW)
#undef DECLW
#define LOADW(j) \
    w0A_##j.x = Whh0[rowA * HIDN + 2*j]; w0A_##j.y = Whh0[rowA * HIDN + 2*j + 1]; \
    w0B_##j.x = Whh0[rowB * HIDN + 2*j]; w0B_##j.y = Whh0[rowB * HIDN + 2*j + 1]; \
    wiA_##j.x = Wih1[rowA * HIDN + 2*j]; wiA_##j.y = Wih1[rowA * HIDN + 2*j + 1]; \
    wiB_##j.x = Wih1[rowB * HIDN + 2*j]; wiB_##j.y = Wih1[rowB * HIDN + 2*j + 1]; \
    whA_##j.x = Whh1[rowA * HIDN + 2*j]; whA_##j.y = Whh1[rowA * HIDN + 2*j + 1]; \
    whB_##j.x = Whh1[rowB * HIDN + 2*j]; whB_##j.y = Whh1[rowB * HIDN + 2*j + 1];
    RJ(LOADW)
#undef LOADW

    float wxAg = Wih0[rowA * 2 + 0], wxAp = Wih0[rowA * 2 + 1];
    float wxBg = Wih0[rowB * 2 + 0], wxBp = Wih0[rowB * 2 + 1];
    float bA0 = bih0[rowA] + bhh0[rowA];
    float bB0 = bih0[rowB] + bhh0[rowB];
    float bA1 = bih1[rowA] + bhh1[rowA];
    float bB1 = bih1[rowB] + bhh1[rowB];
    float wo = valid ? Wout[u] : 0.f;
    const float bo = bout[0];

    // ---- pin per-lane weight constants into VGPRs (defeat remat/sinking) ----
#define PINW(j) asm volatile("" : "+v"(w0A_##j), "+v"(w0B_##j), "+v"(wiA_##j), \
                                  "+v"(wiB_##j), "+v"(whA_##j), "+v"(whB_##j));
    RJ(PINW)
#undef PINW
    asm volatile("" : "+v"(wxAg), "+v"(wxAp), "+v"(wxBg), "+v"(wxBp));
    asm volatile("" : "+v"(bA0), "+v"(bB0), "+v"(bA1), "+v"(bB1), "+v"(wo));

    const float mA = hB ? 2.0f : 1.0f;
    const float dA = hB ? 1.0f : 0.0f;
    const float cA = -1.4426950408889634f * mA;

    float c0 = 0.f, c1 = 0.f;

    const int t0     = blockIdx.x * CHUNK;
    const int tstart = t0 - WARM;

    float xgv, xpv;
    { int ti = tstart + lane; ti = ti < 0 ? 0 : ti; xgv = grad[ti]; xpv = par[ti]; }

    // ---- prologue: h0(tstart) from zero state; h1(tstart-1)=0. Publish. ----
    {
        const float xg0 = bcast(xgv, 0), xp0 = bcast(xpv, 0);
        const float pA = __builtin_fmaf(wxAp, xp0, __builtin_fmaf(wxAg, xg0, bA0));
        const float pB = __builtin_fmaf(wxBp, xp0, __builtin_fmaf(wxBg, xg0, bB0));
        c0 = 0.f;
        const float h0i = gate_update(pA, pB, c0, cA, mA, dA, hB);
        hbuf[u] = h0i;
        hbuf[HIDN + u] = 0.f;
        c1 = 0.f;
    }

#pragma unroll 1
    for (int b = 0; b < NB; ++b) {
        float xgn = 0.f, xpn = 0.f;
        if (b + 1 < NB) {
            int ti = tstart + (b + 1) * 64 + lane;
            ti = ti < 0 ? 0 : (ti >= n ? n - 1 : ti);
            xgn = grad[ti]; xpn = par[ti];
        }
        if (b == WARMB && blockIdx.x == 0) {
            // chunk 0: exact zero-state restart at t=0. Recompute h0(0) from
            // x(0) (lane 0 of this batch), republish h0(0), h1(-1)=0.
            const float xg0 = bcast(xgv, 0), xp0 = bcast(xpv, 0);
            const float pA = __builtin_fmaf(wxAp, xp0, __builtin_fmaf(wxAg, xg0, bA0));
            const float pB = __builtin_fmaf(wxBp, xp0, __builtin_fmaf(wxBg, xg0, bB0));
            c0 = 0.f;
            const float h0i = gate_update(pA, pB, c0, cA, mA, dA, hB);
            hbuf[u] = h0i;
            hbuf[HIDN + u] = 0.f;
            c1 = 0.f;
        }
        const bool main_phase = (b >= WARMB);

#pragma unroll 2
        for (int j = 0; j < 64; ++j) {
            // x(t+1): from this batch, or lane 0 of the next at the seam
            const int ln = (j + 1) & 63;
            const float xgN = bcast((j < 63) ? xgv : xgn, ln);
            const float xpN = bcast((j < 63) ? xpv : xpn, ln);

            // ---- reload pairs published at end of previous iteration ----
            v2f hp0_0, hp0_1, hp0_2, hp0_3, hp0_4, hp0_5, hp0_6, hp0_7, hp0_8, hp0_9;
            v2f hp1_0, hp1_1, hp1_2, hp1_3, hp1_4, hp1_5, hp1_6, hp1_7, hp1_8, hp1_9;
            {
                const float4 r0 = *reinterpret_cast<const float4*>(&hbuf[0]);
                const float4 r1 = *reinterpret_cast<const float4*>(&hbuf[4]);
                const float4 r2 = *reinterpret_cast<const float4*>(&hbuf[8]);
                const float4 r3 = *reinterpret_cast<const float4*>(&hbuf[12]);
                const float4 r4 = *reinterpret_cast<const float4*>(&hbuf[16]);
                hp0_0.x = r0.x; hp0_0.y = r0.y;  hp0_1.x = r0.z; hp0_1.y = r0.w;
                hp0_2.x = r1.x; hp0_2.y = r1.y;  hp0_3.x = r1.z; hp0_3.y = r1.w;
                hp0_4.x = r2.x; hp0_4.y = r2.y;  hp0_5.x = r2.z; hp0_5.y = r2.w;
                hp0_6.x = r3.x; hp0_6.y = r3.y;  hp0_7.x = r3.z; hp0_7.y = r3.w;
                hp0_8.x = r4.x; hp0_8.y = r4.y;  hp0_9.x = r4.z; hp0_9.y = r4.w;
                const float4 s0 = *reinterpret_cast<const float4*>(&hbuf[20]);
                const float4 s1 = *reinterpret_cast<const float4*>(&hbuf[24]);
                const float4 s2 = *reinterpret_cast<const float4*>(&hbuf[28]);
                const float4 s3 = *reinterpret_cast<const float4*>(&hbuf[32]);
                const float4 s4 = *reinterpret_cast<const float4*>(&hbuf[36]);
                hp1_0.x = s0.x; hp1_0.y = s0.y;  hp1_1.x = s0.z; hp1_1.y = s0.w;
                hp1_2.x = s1.x; hp1_2.y = s1.y;  hp1_3.x = s1.z; hp1_3.y = s1.w;
                hp1_4.x = s2.x; hp1_4.y = s2.y;  hp1_5.x = s2.z; hp1_5.y = s2.w;
                hp1_6.x = s3.x; hp1_6.y = s3.y;  hp1_7.x = s3.z; hp1_7.y = s3.w;
                hp1_8.x = s4.x; hp1_8.y = s4.y;  hp1_9.x = s4.z; hp1_9.y = s4.w;
            }

            // ---- L1(t) matvec: h1 preact from hp0 (=h0(t)) and hp1 (=h1(t-1)) ----
            v2f qA = {0.f, 0.f}, qB = {0.f, 0.f}, qA2 = {0.f, 0.f}, qB2 = {0.f, 0.f};
#define F1A(j_) qA  = fma2(wiA_##j_, hp0_##j_, qA);  qB  = fma2(wiB_##j_, hp0_##j_, qB);
#define F1B(j_) qA2 = fma2(whA_##j_, hp1_##j_, qA2); qB2 = fma2(whB_##j_, hp1_##j_, qB2);
            RJ(F1A) RJ(F1B)
#undef F1A
#undef F1B

            // ---- L0(t+1) matvec: h0 preact from hp0 and x(t+1) (independent) ----
            v2f aA = {0.f, 0.f}, aB = {0.f, 0.f}, aA2 = {0.f, 0.f}, aB2 = {0.f, 0.f};
#define F0A(j_) aA  = fma2(w0A_##j_, hp0_##j_, aA);  aB  = fma2(w0B_##j_, hp0_##j_, aB);
#define F0B(j_) aA2 = fma2(w0A_##j_, hp0_##j_, aA2); aB2 = fma2(w0B_##j_, hp0_##j_, aB2);
            RJA(F0A) RJB(F0B)
#undef F0A
#undef F0B

            const float a1A = ((qA.x + qA.y) + (qA2.x + qA2.y)) + bA1;
            const float a1B = ((qB.x + qB.y) + (qB2.x + qB2.y)) + bB1;
            const float xpA = __builtin_fmaf(wxAp, xpN, __builtin_fmaf(wxAg, xgN, bA0));
            const float xpB = __builtin_fmaf(wxBp, xpN, __builtin_fmaf(wxBg, xgN, bB0));
            const float a0A = ((aA.x + aA.y) + (aA2.x + aA2.y)) + xpA;
            const float a0B = ((aB.x + aB.y) + (aB2.x + aB2.y)) + xpB;

            // ---- two independent gate chains ----
            const float h1cur  = gate_update(a1A, a1B, c1, cA, mA, dA, hB);  // h1(t)
            const float h0next = gate_update(a0A, a0B, c0, cA, mA, dA, hB);  // h0(t+1)

            // ---- publish for next iteration ----
            hbuf[u] = h0next;
            hbuf[HIDN + u] = h1cur;

            // ---- deferred head: park h1(t)*wo, reduce at batch end ----
            hstore[j][wcol] = h1cur * wo;          // dup/pad writes benign (bit-identical)
        }

        if (main_phase) {
            // each lane reduces ONE step's 20 contributions (5x ds_read_b128)
            const float4 a0 = *reinterpret_cast<const float4*>(&hstore[lane][0]);
            const float4 a1 = *reinterpret_cast<const float4*>(&hstore[lane][4]);
            const float4 a2 = *reinterpret_cast<const float4*>(&hstore[lane][8]);
            const float4 a3 = *reinterpret_cast<const float4*>(&hstore[lane][12]);
            const float4 a4 = *reinterpret_cast<const float4*>(&hstore[lane][16]);
            float s = (((a0.x + a0.y) + (a0.z + a0.w)) +
                       ((a1.x + a1.y) + (a1.z + a1.w))) +
                      (((a2.x + a2.y) + (a2.z + a2.w)) +
                       ((a3.x + a3.y) + (a3.z + a3.w))) +
                      ((a4.x + a4.y) + (a4.z + a4.w));
            int t = tstart + b * 64 + lane;
            if (t >= 0 && t < n) out[t] = s + bo;  // coalesced
        }
        xgv = xgn; xpv = xpn;
    }
}

extern "C" void kernel_launch(void* const* d_in, const int* in_sizes, int n_in,
                              void* d_out, int out_size, void* d_ws, size_t ws_size,
                              hipStream_t stream) {
    const float* grad = (const float*)d_in[0];
    const float* par  = (const float*)d_in[1];
    const float* Wih0 = (const float*)d_in[2];
    const float* Whh0 = (const float*)d_in[3];
    const float* bih0 = (const float*)d_in[4];
    const float* bhh0 = (const float*)d_in[5];
    const float* Wih1 = (const float*)d_in[6];
    const float* Whh1 = (const float*)d_in[7];
    const float* bih1 = (const float*)d_in[8];
    const float* bhh1 = (const float*)d_in[9];
    const float* Wout = (const float*)d_in[10];
    const float* bout = (const float*)d_in[11];
    float* out = (float*)d_out;

    const int n = in_sizes[0];
    const int chunks = (n + CHUNK - 1) / CHUNK;   // 4096 for n=524288 -> 4 waves/SIMD

    lstm_opt_kernel<<<chunks, 64, 0, stream>>>(grad, par, Wih0, Whh0, bih0, bhh0,
                                               Wih1, Whh1, bih1, bhh1, Wout, bout,
                                               out, n);
}

// Round 17
// 206.298 us; speedup vs baseline: 11.8010x; 11.8010x over previous
//
#include <hip/hip_runtime.h>

#define HIDN 20
#define CHUNK 256
#define WARM 64
#define NB ((CHUNK + WARM) / 64)   // 5 batches of 64 steps
#define WARMB (WARM / 64)          // first batch is warmup

typedef float v2f __attribute__((ext_vector_type(2)));
typedef unsigned int v2u __attribute__((ext_vector_type(2)));

__device__ __forceinline__ float bcast(float v, int l) {
    return __int_as_float(__builtin_amdgcn_readlane(__float_as_int(v), l));
}
__device__ __forceinline__ v2f fma2(v2f a, v2f b, v2f c) {
    return __builtin_elementwise_fma(a, b, c);      // -> v_pk_fma_f32 (all-VGPR)
}
// lane[i] <-> lane[i^32] exchange, direction-agnostic (bit-exact):
// permlane32_swap with equal inputs returns {g, g[lane^32]} in some order;
// r.x^r.y^g isolates the exchanged value. VALU pipe, no DS round trip.
__device__ __forceinline__ float xchg32(float g) {
#if __has_builtin(__builtin_amdgcn_permlane32_swap)
    const unsigned int gu = __float_as_uint(g);
    const v2u r = __builtin_amdgcn_permlane32_swap(gu, gu, false, false);
    return __uint_as_float(r.x ^ r.y ^ gu);
#else
    return __shfl_xor(g, 32);
#endif
}

// gate-split LSTM cell epilogue (f32). Half A lanes hold gate pre-acts (i,f),
// half B lanes hold (g,o) for the same unit.
__device__ __forceinline__ float gate_update(float aA, float aB, float& c,
                                             float cA, float mA, float dA,
                                             bool hB) {
    const float cB = -1.4426950408889634f;
    const float cT =  2.8853900817779268f;
    float eA = __builtin_amdgcn_exp2f(cA * aA);
    float sA = __builtin_amdgcn_rcpf(1.0f + eA);
    float gA = __builtin_fmaf(mA, sA, -dA);          // i (half A) / g (half B)
    float eB = __builtin_amdgcn_exp2f(cB * aB);
    float gB = __builtin_amdgcn_rcpf(1.0f + eB);     // f (half A) / o (half B)
    float oA = xchg32(gA);
    float oB = xchg32(gB);
    float f = hB ? oB : gB;
    float o = hB ? gB : oB;
    c = __builtin_fmaf(f, c, gA * oA);
    float ec = __builtin_amdgcn_exp2f(cT * c);
    float tc = 1.0f - 2.0f * __builtin_amdgcn_rcpf(ec + 1.0f);
    return o * tc;
}

#define RJA(M) M(0) M(1) M(2) M(3) M(4)
#define RJB(M) M(5) M(6) M(7) M(8) M(9)
#define RJ(M) RJA(M) RJB(M)

// One 64-lane wave = one chunk of CHUNK steps (WARM discarded warmup steps).
// Software-pipelined layers (L1(t) ∥ L0(t+1)); h broadcast via 160 B LDS
// buffer; deferred output head via hstore. x-window loaded PRE-SHIFTED by 1
// so the loop body needs no seam selects (bit-identical inputs to r15).
// 2 waves/SIMD is the spill-free max (r16: 4 waves -> budget 128 -> spill).
__global__ __launch_bounds__(64)
__attribute__((amdgpu_waves_per_eu(2, 2)))
void lstm_opt_kernel(const float* __restrict__ grad, const float* __restrict__ par,
                     const float* __restrict__ Wih0, const float* __restrict__ Whh0,
                     const float* __restrict__ bih0, const float* __restrict__ bhh0,
                     const float* __restrict__ Wih1, const float* __restrict__ Whh1,
                     const float* __restrict__ bih1, const float* __restrict__ bhh1,
                     const float* __restrict__ Wout, const float* __restrict__ bout,
                     float* __restrict__ out, int n)
{
    __shared__ __align__(16) float hbuf[40];        // [0..19]=h0(t), [20..39]=h1(t-1)
    __shared__ __align__(16) float hstore[64][24];  // per-step h1*wo, stride 24

    const int lane  = threadIdx.x;
    const int lh    = lane & 31;
    const bool hB   = lane >= 32;
    const int u     = (lh < HIDN) ? lh : (HIDN - 1);
    const bool valid = (lh < HIDN);
    // invalid lanes park their (zero) head writes in pad columns 20..23
    const int wcol  = valid ? lh : (HIDN + (lane & 3));

    const int rowA = (hB ? 2 : 0) * HIDN + u;   // i-row or g-row
    const int rowB = (hB ? 3 : 1) * HIDN + u;   // f-row or o-row

    // ---- k-paired register weights (named v2f scalars; no arrays) ----
#define DECLW(j) v2f w0A_##j, w0B_##j, wiA_##j, wiB_##j, whA_##j, whB_##j;
    RJ(DECLW)
#undef DECLW
#define LOADW(j) \
    w0A_##j.x = Whh0[rowA * HIDN + 2*j]; w0A_##j.y = Whh0[rowA * HIDN + 2*j + 1]; \
    w0B_##j.x = Whh0[rowB * HIDN + 2*j]; w0B_##j.y = Whh0[rowB * HIDN + 2*j + 1]; \
    wiA_##j.x = Wih1[rowA * HIDN + 2*j]; wiA_##j.y = Wih1[rowA * HIDN + 2*j + 1]; \
    wiB_##j.x = Wih1[rowB * HIDN + 2*j]; wiB_##j.y = Wih1[rowB * HIDN + 2*j + 1]; \
    whA_##j.x = Whh1[rowA * HIDN + 2*j]; whA_##j.y = Whh1[rowA * HIDN + 2*j + 1]; \
    whB_##j.x = Whh1[rowB * HIDN + 2*j]; whB_##j.y = Whh1[rowB * HIDN + 2*j + 1];
    RJ(LOADW)
#undef LOADW

    float wxAg = Wih0[rowA * 2 + 0], wxAp = Wih0[rowA * 2 + 1];
    float wxBg = Wih0[rowB * 2 + 0], wxBp = Wih0[rowB * 2 + 1];
    float bA0 = bih0[rowA] + bhh0[rowA];
    float bB0 = bih0[rowB] + bhh0[rowB];
    float bA1 = bih1[rowA] + bhh1[rowA];
    float bB1 = bih1[rowB] + bhh1[rowB];
    float wo = valid ? Wout[u] : 0.f;
    const float bo = bout[0];

    // ---- pin per-lane weight constants into VGPRs (defeat remat/sinking) ----
#define PINW(j) asm volatile("" : "+v"(w0A_##j), "+v"(w0B_##j), "+v"(wiA_##j), \
                                  "+v"(wiB_##j), "+v"(whA_##j), "+v"(whB_##j));
    RJ(PINW)
#undef PINW
    asm volatile("" : "+v"(wxAg), "+v"(wxAp), "+v"(wxBg), "+v"(wxBp));
    asm volatile("" : "+v"(bA0), "+v"(bB0), "+v"(bA1), "+v"(bB1), "+v"(wo));

    const float mA = hB ? 2.0f : 1.0f;
    const float dA = hB ? 1.0f : 0.0f;
    const float cA = -1.4426950408889634f * mA;

    float c0 = 0.f, c1 = 0.f;

    const int t0     = blockIdx.x * CHUNK;
    const int tstart = t0 - WARM;

    // shifted x-window for batch 0: x(tstart + 1 + lane)
    float xsg, xsp;
    {
        int ti = tstart + 1 + lane;
        ti = ti < 0 ? 0 : (ti >= n ? n - 1 : ti);
        xsg = grad[ti]; xsp = par[ti];
    }

    // ---- prologue: h0(tstart) from zero state; h1(tstart-1)=0. Publish. ----
    {
        const int tc0 = tstart < 0 ? 0 : tstart;
        const float xg0 = grad[tc0], xp0 = par[tc0];      // uniform one-time loads
        const float pA = __builtin_fmaf(wxAp, xp0, __builtin_fmaf(wxAg, xg0, bA0));
        const float pB = __builtin_fmaf(wxBp, xp0, __builtin_fmaf(wxBg, xg0, bB0));
        c0 = 0.f;
        const float h0i = gate_update(pA, pB, c0, cA, mA, dA, hB);
        hbuf[u] = h0i;
        hbuf[HIDN + u] = 0.f;
        c1 = 0.f;
    }

#pragma unroll 1
    for (int b = 0; b < NB; ++b) {
        float xng = 0.f, xnp = 0.f;
        if (b + 1 < NB) {
            int ti = tstart + (b + 1) * 64 + 1 + lane;
            ti = ti < 0 ? 0 : (ti >= n ? n - 1 : ti);
            xng = grad[ti]; xnp = par[ti];
        }
        if (b == WARMB && blockIdx.x == 0) {
            // chunk 0: exact zero-state restart at t=0. Recompute h0(0) from
            // x(0), republish h0(0), h1(-1)=0.
            const float xg0 = grad[0], xp0 = par[0];      // uniform loads
            const float pA = __builtin_fmaf(wxAp, xp0, __builtin_fmaf(wxAg, xg0, bA0));
            const float pB = __builtin_fmaf(wxBp, xp0, __builtin_fmaf(wxBg, xg0, bB0));
            c0 = 0.f;
            const float h0i = gate_update(pA, pB, c0, cA, mA, dA, hB);
            hbuf[u] = h0i;
            hbuf[HIDN + u] = 0.f;
            c1 = 0.f;
        }
        const bool main_phase = (b >= WARMB);

#pragma unroll 2
        for (int j = 0; j < 64; ++j) {
            // x(t+1) straight from the pre-shifted window -- no seam selects
            const float xgN = bcast(xsg, j);
            const float xpN = bcast(xsp, j);

            // ---- reload pairs published at end of previous iteration ----
            v2f hp0_0, hp0_1, hp0_2, hp0_3, hp0_4, hp0_5, hp0_6, hp0_7, hp0_8, hp0_9;
            v2f hp1_0, hp1_1, hp1_2, hp1_3, hp1_4, hp1_5, hp1_6, hp1_7, hp1_8, hp1_9;
            {
                const float4 r0 = *reinterpret_cast<const float4*>(&hbuf[0]);
                const float4 r1 = *reinterpret_cast<const float4*>(&hbuf[4]);
                const float4 r2 = *reinterpret_cast<const float4*>(&hbuf[8]);
                const float4 r3 = *reinterpret_cast<const float4*>(&hbuf[12]);
                const float4 r4 = *reinterpret_cast<const float4*>(&hbuf[16]);
                hp0_0.x = r0.x; hp0_0.y = r0.y;  hp0_1.x = r0.z; hp0_1.y = r0.w;
                hp0_2.x = r1.x; hp0_2.y = r1.y;  hp0_3.x = r1.z; hp0_3.y = r1.w;
                hp0_4.x = r2.x; hp0_4.y = r2.y;  hp0_5.x = r2.z; hp0_5.y = r2.w;
                hp0_6.x = r3.x; hp0_6.y = r3.y;  hp0_7.x = r3.z; hp0_7.y = r3.w;
                hp0_8.x = r4.x; hp0_8.y = r4.y;  hp0_9.x = r4.z; hp0_9.y = r4.w;
                const float4 s0 = *reinterpret_cast<const float4*>(&hbuf[20]);
                const float4 s1 = *reinterpret_cast<const float4*>(&hbuf[24]);
                const float4 s2 = *reinterpret_cast<const float4*>(&hbuf[28]);
                const float4 s3 = *reinterpret_cast<const float4*>(&hbuf[32]);
                const float4 s4 = *reinterpret_cast<const float4*>(&hbuf[36]);
                hp1_0.x = s0.x; hp1_0.y = s0.y;  hp1_1.x = s0.z; hp1_1.y = s0.w;
                hp1_2.x = s1.x; hp1_2.y = s1.y;  hp1_3.x = s1.z; hp1_3.y = s1.w;
                hp1_4.x = s2.x; hp1_4.y = s2.y;  hp1_5.x = s2.z; hp1_5.y = s2.w;
                hp1_6.x = s3.x; hp1_6.y = s3.y;  hp1_7.x = s3.z; hp1_7.y = s3.w;
                hp1_8.x = s4.x; hp1_8.y = s4.y;  hp1_9.x = s4.z; hp1_9.y = s4.w;
            }

            // ---- L1(t) matvec: h1 preact from hp0 (=h0(t)) and hp1 (=h1(t-1)) ----
            v2f qA = {0.f, 0.f}, qB = {0.f, 0.f}, qA2 = {0.f, 0.f}, qB2 = {0.f, 0.f};
#define F1A(j_) qA  = fma2(wiA_##j_, hp0_##j_, qA);  qB  = fma2(wiB_##j_, hp0_##j_, qB);
#define F1B(j_) qA2 = fma2(whA_##j_, hp1_##j_, qA2); qB2 = fma2(whB_##j_, hp1_##j_, qB2);
            RJ(F1A) RJ(F1B)
#undef F1A
#undef F1B

            // ---- L0(t+1) matvec: h0 preact from hp0 and x(t+1) (independent) ----
            v2f aA = {0.f, 0.f}, aB = {0.f, 0.f}, aA2 = {0.f, 0.f}, aB2 = {0.f, 0.f};
#define F0A(j_) aA  = fma2(w0A_##j_, hp0_##j_, aA);  aB  = fma2(w0B_##j_, hp0_##j_, aB);
#define F0B(j_) aA2 = fma2(w0A_##j_, hp0_##j_, aA2); aB2 = fma2(w0B_##j_, hp0_##j_, aB2);
            RJA(F0A) RJB(F0B)
#undef F0A
#undef F0B

            const float a1A = ((qA.x + qA.y) + (qA2.x + qA2.y)) + bA1;
            const float a1B = ((qB.x + qB.y) + (qB2.x + qB2.y)) + bB1;
            const float xpA = __builtin_fmaf(wxAp, xpN, __builtin_fmaf(wxAg, xgN, bA0));
            const float xpB = __builtin_fmaf(wxBp, xpN, __builtin_fmaf(wxBg, xgN, bB0));
            const float a0A = ((aA.x + aA.y) + (aA2.x + aA2.y)) + xpA;
            const float a0B = ((aB.x + aB.y) + (aB2.x + aB2.y)) + xpB;

            // ---- two independent gate chains ----
            const float h1cur  = gate_update(a1A, a1B, c1, cA, mA, dA, hB);  // h1(t)
            const float h0next = gate_update(a0A, a0B, c0, cA, mA, dA, hB);  // h0(t+1)

            // ---- publish for next iteration ----
            hbuf[u] = h0next;
            hbuf[HIDN + u] = h1cur;

            // ---- deferred head: park h1(t)*wo, reduce at batch end ----
            hstore[j][wcol] = h1cur * wo;          // dup/pad writes benign (bit-identical)
        }

        if (main_phase) {
            // each lane reduces ONE step's 20 contributions (5x ds_read_b128)
            const float4 a0 = *reinterpret_cast<const float4*>(&hstore[lane][0]);
            const float4 a1 = *reinterpret_cast<const float4*>(&hstore[lane][4]);
            const float4 a2 = *reinterpret_cast<const float4*>(&hstore[lane][8]);
            const float4 a3 = *reinterpret_cast<const float4*>(&hstore[lane][12]);
            const float4 a4 = *reinterpret_cast<const float4*>(&hstore[lane][16]);
            float s = (((a0.x + a0.y) + (a0.z + a0.w)) +
                       ((a1.x + a1.y) + (a1.z + a1.w))) +
                      (((a2.x + a2.y) + (a2.z + a2.w)) +
                       ((a3.x + a3.y) + (a3.z + a3.w))) +
                      ((a4.x + a4.y) + (a4.z + a4.w));
            int t = tstart + b * 64 + lane;
            if (t >= 0 && t < n) out[t] = s + bo;  // coalesced
        }
        xsg = xng; xsp = xnp;
    }
}

extern "C" void kernel_launch(void* const* d_in, const int* in_sizes, int n_in,
                              void* d_out, int out_size, void* d_ws, size_t ws_size,
                              hipStream_t stream) {
    const float* grad = (const float*)d_in[0];
    const float* par  = (const float*)d_in[1];
    const float* Wih0 = (const float*)d_in[2];
    const float* Whh0 = (const float*)d_in[3];
    const float* bih0 = (const float*)d_in[4];
    const float* bhh0 = (const float*)d_in[5];
    const float* Wih1 = (const float*)d_in[6];
    const float* Whh1 = (const float*)d_in[7];
    const float* bih1 = (const float*)d_in[8];
    const float* bhh1 = (const float*)d_in[9];
    const float* Wout = (const float*)d_in[10];
    const float* bout = (const float*)d_in[11];
    float* out = (float*)d_out;

    const int n = in_sizes[0];
    const int chunks = (n + CHUNK - 1) / CHUNK;   // 2048 for n=524288 -> 2 waves/SIMD

    lstm_opt_kernel<<<chunks, 64, 0, stream>>>(grad, par, Wih0, Whh0, bih0, bhh0,
                                               Wih1, Whh1, bih1, bhh1, Wout, bout,
                                               out, n);
}